// Round 2
// baseline (526.990 us; speedup 1.0000x reference)
//
#include <hip/hip_runtime.h>
#include <math.h>

#define N_NODES 10000
#define N_EDGES 320000

__device__ __forceinline__ float ssp(float x) {
    // softplus(x) - ln(2), numerically stable
    float ax = fabsf(x);
    return fmaxf(x, 0.0f) + log1pf(expf(-ax)) - 0.69314718055994531f;
}

__device__ __forceinline__ float bcast_lane(float v, int lane) {
    return __uint_as_float(__builtin_amdgcn_readlane(__float_as_uint(v), lane));
}

// ---------------- CSR build ----------------

__global__ void count_kernel(const int* __restrict__ dst, int* __restrict__ counts, int E) {
    int e = blockIdx.x * blockDim.x + threadIdx.x;
    if (e < E) atomicAdd(&counts[dst[e]], 1);
}

__global__ __launch_bounds__(1024) void scan_kernel(const int* __restrict__ counts,
                                                    int* __restrict__ offsets,
                                                    int* __restrict__ cursor, int n) {
    __shared__ int sums[1024];
    int t = threadIdx.x;
    const int CH = (n + 1023) / 1024;
    int base = t * CH;
    int local = 0;
    for (int i = 0; i < CH; ++i) {
        int idx = base + i;
        if (idx < n) local += counts[idx];
    }
    sums[t] = local;
    __syncthreads();
    for (int off = 1; off < 1024; off <<= 1) {
        int v = sums[t];
        int add = (t >= off) ? sums[t - off] : 0;
        __syncthreads();
        sums[t] = v + add;
        __syncthreads();
    }
    int run = (t == 0) ? 0 : sums[t - 1];  // exclusive prefix
    for (int i = 0; i < CH; ++i) {
        int idx = base + i;
        if (idx < n) {
            offsets[idx] = run;
            cursor[idx]  = run;
            run += counts[idx];
        }
    }
    if (t == 0) offsets[n] = sums[1023];
}

__global__ void scatter_kernel(const int* __restrict__ dst, int* __restrict__ cursor,
                               int* __restrict__ csr, int E) {
    int e = blockIdx.x * blockDim.x + threadIdx.x;
    if (e < E) {
        int d = dst[e];
        int p = atomicAdd(&cursor[d], 1);
        csr[p] = e;
    }
}

// ---------------- node pre-transform: x0 = f0@W1_0/8, x1T[(n,3,64)] = (f1.c @ W1_1)/8 ----------------

__global__ __launch_bounds__(256) void node_pre_kernel(
        const float* __restrict__ nf0, const float* __restrict__ nf1,
        const float* __restrict__ W1_0, const float* __restrict__ W1_1,
        float* __restrict__ x0, float* __restrict__ x1T) {
    const int n = blockIdx.x;
    const int t = threadIdx.x;
    __shared__ float s_f0[64];
    __shared__ float s_f1[192];
    if (t < 64) s_f0[t] = nf0[n*64 + t];
    else        s_f1[t-64] = nf1[n*192 + (t-64)];
    __syncthreads();
    if (t < 64) {
        float acc = 0.f;
        #pragma unroll 8
        for (int u = 0; u < 64; ++u) acc += s_f0[u] * W1_0[u*64 + t];
        x0[n*64 + t] = acc * 0.125f;
    } else {
        const int c = (t - 64) >> 6;
        const int w = t & 63;
        float acc = 0.f;
        #pragma unroll 8
        for (int u = 0; u < 64; ++u) acc += s_f1[u*3 + c] * W1_1[u*64 + w];
        x1T[n*192 + c*64 + w] = acc * 0.125f;
    }
}

// ---------------- main: barrier-free edge loop + epilogue ----------------

__global__ __launch_bounds__(256) void node_main_kernel(
    const float* __restrict__ nf0, const float* __restrict__ nf1,
    const float* __restrict__ nattr,
    const float* __restrict__ eemb, const float* __restrict__ eattr,
    const int* __restrict__ esrc,
    const int* __restrict__ offsets, const int* __restrict__ csr,
    const float* __restrict__ x0g, const float* __restrict__ x1g,
    const float* __restrict__ Wr1, const float* __restrict__ Wr2,
    const float* __restrict__ W2_0, const float* __restrict__ W2_1,
    const float* __restrict__ Wsc0, const float* __restrict__ Wsc1,
    float* __restrict__ out)
{
    const int n = blockIdx.x;
    const int t = threadIdx.x;
    const int u = t & 63;      // lane
    const int g = t >> 6;      // wave id (0..3)

    __shared__ float s_f0[64], s_f1[192], s_attr[4];
    __shared__ float s_agg0[128], s_agg1[384];   // agg1: [c][i], i<64=m01 row u, i>=64=m10 row u
    __shared__ float s_fa[256];
    __shared__ float s_n0[128];
    __shared__ float s_out[256];

    if (t < 64) s_f0[t] = nf0[n*64 + t];
    else        s_f1[t-64] = nf1[n*192 + (t-64)];
    if (t >= 192 && t < 196) s_attr[t-192] = nattr[n*4 + (t-192)];

    const float rs8 = 0.35355339059327373f;   // 1/sqrt(8)
    const float rs3 = 0.57735026918962576f;   // 1/sqrt(3)

    // loop-invariant Wr2 columns (rs8 folded in)
    const int colA = (g == 0) ? u : (64 + u);
    const int colB = (g == 0) ? (192 + u) : (128 + u);
    float wr2a[8], wr2b[8];
    #pragma unroll
    for (int j = 0; j < 8; ++j) {
        wr2a[j] = Wr2[j*256 + colA] * rs8;
        wr2b[j] = Wr2[j*256 + colB] * rs8;
    }
    // loop-invariant Wr1 column for lanes 0..7 (rs8 folded in)
    float wr1c[8];
    #pragma unroll
    for (int i = 0; i < 8; ++i)
        wr1c[i] = (u < 8) ? Wr1[i*8 + u] * rs8 : 0.f;

    float a0 = 0.f, a1 = 0.f;
    const int start = offsets[n];
    const int end   = offsets[n+1];

    // prefetched edge index chain
    int e   = (start < end) ? csr[start] : 0;
    int src = (start < end) ? esrc[e] : 0;

    for (int idx = start; idx < end; ++idx) {
        const int e_cur = e, src_cur = src;
        if (idx + 1 < end) { e = csr[idx+1]; src = esrc[e]; }

        // h_j (wave-uniform): lanes 0..7 compute, broadcast via readlane
        float pre = 0.f;
        if (u < 8) {
            #pragma unroll
            for (int i = 0; i < 8; ++i) pre += eemb[e_cur*8 + i] * wr1c[i];
            pre = ssp(pre);
        }
        float wa = 0.f, wb = 0.f;
        #pragma unroll
        for (int j = 0; j < 8; ++j) {
            const float hj = bcast_lane(pre, j);
            wa += hj * wr2a[j];
            wb += hj * wr2b[j];
        }

        const float4 y = *reinterpret_cast<const float4*>(eattr + e_cur*4);

        if (g == 0) {
            const float xs0 = x0g[src_cur*64 + u];
            const float xa = x1g[src_cur*192 + u];
            const float xb = x1g[src_cur*192 + 64 + u];
            const float xc = x1g[src_cur*192 + 128 + u];
            a0 += wa * xs0 * y.x;                                   // m00[u]
            a1 += wb * (xa*y.y + xb*y.z + xc*y.w) * rs3;            // m11[u]
        } else {
            const int c = g - 1;
            const float xs0 = x0g[src_cur*64 + u];
            const float xs1 = x1g[src_cur*192 + c*64 + u];
            const float yc  = (c == 0) ? y.y : ((c == 1) ? y.z : y.w);
            a0 += wa * xs0 * yc;                                    // m01[u][c]
            a1 += wb * xs1 * y.x;                                   // m10[u][c]
        }
    }

    const float rs32 = 0.17677669529663687f;  // 1/sqrt(32)
    if (g == 0) {
        s_agg0[u]      = a0 * rs32;
        s_agg0[64+u]   = a1 * rs32;
    } else {
        const int c = g - 1;
        s_agg1[c*128 + u]      = a0 * rs32;
        s_agg1[c*128 + 64 + u] = a1 * rs32;
    }
    __syncthreads();
    s_fa[t] = s_f0[t >> 2] * s_attr[t & 3];
    __syncthreads();

    const float rs128 = 0.088388347648318447f;  // 1/sqrt(128)
    if (t < 128) {
        float acc = 0.f;
        #pragma unroll 4
        for (int i = 0; i < 128; ++i) acc += s_agg0[i] * W2_0[i*128 + t];
        acc *= rs128;
        float sc = 0.f;
        #pragma unroll 4
        for (int uv = 0; uv < 256; ++uv) sc += s_fa[uv] * Wsc0[uv*128 + t];
        acc += sc * 0.0625f;
        s_n0[t] = ssp(acc);  // scalars (t<64) and gates (t>=64)
    }
    __syncthreads();
    if (t < 64) s_out[t] = s_f0[t] + s_n0[t];
    if (t < 192) {
        const int w = t & 63;
        const int c = t >> 6;
        float acc = 0.f;
        #pragma unroll 4
        for (int i = 0; i < 128; ++i) acc += s_agg1[c*128 + i] * W2_1[i*64 + w];
        acc *= rs128;
        float sc = 0.f;
        #pragma unroll 4
        for (int uu = 0; uu < 64; ++uu) {
            const float* wp = Wsc1 + uu*256 + w;  // (uu*4+v)*64 + w
            float wv = s_attr[0]*wp[0] + s_attr[1]*wp[64] + s_attr[2]*wp[128] + s_attr[3]*wp[192];
            sc += s_f1[uu*3 + c] * wv;
        }
        acc += sc * 0.0625f;
        const float gated = acc * s_n0[64 + w];
        s_out[64 + w*3 + c] = s_f1[w*3 + c] + gated;
    }
    __syncthreads();
    out[n*256 + t] = s_out[t];
}

// ---------------- launch ----------------

extern "C" void kernel_launch(void* const* d_in, const int* in_sizes, int n_in,
                              void* d_out, int out_size, void* d_ws, size_t ws_size,
                              hipStream_t stream) {
    const float* nf0   = (const float*)d_in[0];
    const float* nf1   = (const float*)d_in[1];
    const float* nattr = (const float*)d_in[2];
    const float* eemb  = (const float*)d_in[3];
    const float* eattr = (const float*)d_in[4];
    const int*   esrc  = (const int*)d_in[5];
    const int*   edst  = (const int*)d_in[6];
    const float* W1_0  = (const float*)d_in[7];
    const float* W1_1  = (const float*)d_in[8];
    const float* Wr1   = (const float*)d_in[9];
    const float* Wr2   = (const float*)d_in[10];
    const float* W2_0  = (const float*)d_in[11];
    const float* W2_1  = (const float*)d_in[12];
    const float* Wsc0  = (const float*)d_in[13];
    const float* Wsc1  = (const float*)d_in[14];
    float* out = (float*)d_out;

    char* ws = (char*)d_ws;
    float* x0  = (float*)ws;   ws += (size_t)N_NODES*64*sizeof(float);
    float* x1T = (float*)ws;   ws += (size_t)N_NODES*192*sizeof(float);
    int* counts  = (int*)ws;   ws += (size_t)N_NODES*sizeof(int);
    int* offsets = (int*)ws;   ws += (size_t)(N_NODES+1)*sizeof(int);
    int* cursor  = (int*)ws;   ws += (size_t)N_NODES*sizeof(int);
    int* csr     = (int*)ws;   ws += (size_t)N_EDGES*sizeof(int);

    hipMemsetAsync(counts, 0, N_NODES*sizeof(int), stream);
    node_pre_kernel<<<N_NODES, 256, 0, stream>>>(nf0, nf1, W1_0, W1_1, x0, x1T);
    count_kernel<<<(N_EDGES+255)/256, 256, 0, stream>>>(edst, counts, N_EDGES);
    scan_kernel<<<1, 1024, 0, stream>>>(counts, offsets, cursor, N_NODES);
    scatter_kernel<<<(N_EDGES+255)/256, 256, 0, stream>>>(edst, cursor, csr, N_EDGES);
    node_main_kernel<<<N_NODES, 256, 0, stream>>>(nf0, nf1, nattr, eemb, eattr, esrc,
        offsets, csr, x0, x1T, Wr1, Wr2, W2_0, W2_1, Wsc0, Wsc1, out);
}

// Round 4
// 258.795 us; speedup vs baseline: 2.0363x; 2.0363x over previous
//
#include <hip/hip_runtime.h>
#include <math.h>

#define N_NODES 10000
#define N_EDGES 320000

__device__ __forceinline__ float ssp(float x) {
    float ax = fabsf(x);
    return fmaxf(x, 0.0f) + log1pf(expf(-ax)) - 0.69314718055994531f;
}
__device__ __forceinline__ float bcastf(float v, int l) {
    return __uint_as_float(__builtin_amdgcn_readlane(__float_as_uint(v), l));
}
__device__ __forceinline__ int bcasti(int v, int l) {
    return __builtin_amdgcn_readlane(v, l);
}

// ---------------- CSR build ----------------

__global__ void count_kernel(const int* __restrict__ dst, int* __restrict__ counts, int E) {
    int e = blockIdx.x * blockDim.x + threadIdx.x;
    if (e < E) atomicAdd(&counts[dst[e]], 1);
}

__global__ __launch_bounds__(1024) void scan_kernel(const int* __restrict__ counts,
                                                    int* __restrict__ offsets,
                                                    int* __restrict__ cursor, int n) {
    __shared__ int sums[1024];
    int t = threadIdx.x;
    const int CH = (n + 1023) / 1024;
    int base = t * CH;
    int local = 0;
    for (int i = 0; i < CH; ++i) {
        int idx = base + i;
        if (idx < n) local += counts[idx];
    }
    sums[t] = local;
    __syncthreads();
    for (int off = 1; off < 1024; off <<= 1) {
        int v = sums[t];
        int add = (t >= off) ? sums[t - off] : 0;
        __syncthreads();
        sums[t] = v + add;
        __syncthreads();
    }
    int run = (t == 0) ? 0 : sums[t - 1];
    for (int i = 0; i < CH; ++i) {
        int idx = base + i;
        if (idx < n) {
            offsets[idx] = run;
            cursor[idx]  = run;
            run += counts[idx];
        }
    }
    if (t == 0) offsets[n] = sums[1023];
}

__global__ void scatter_kernel(const int* __restrict__ dst, int* __restrict__ cursor,
                               int* __restrict__ csr, int E) {
    int e = blockIdx.x * blockDim.x + threadIdx.x;
    if (e < E) {
        int d = dst[e];
        int p = atomicAdd(&cursor[d], 1);
        csr[p] = e;
    }
}

// ---------------- node pre-transform ----------------

__global__ __launch_bounds__(256) void node_pre_kernel(
        const float* __restrict__ nf0, const float* __restrict__ nf1,
        const float* __restrict__ W1_0, const float* __restrict__ W1_1,
        float* __restrict__ x0, float* __restrict__ x1T) {
    const int n = blockIdx.x;
    const int t = threadIdx.x;
    __shared__ float s_f0[64];
    __shared__ float s_f1[192];
    if (t < 64) s_f0[t] = nf0[n*64 + t];
    else        s_f1[t-64] = nf1[n*192 + (t-64)];
    __syncthreads();
    if (t < 64) {
        float acc = 0.f;
        #pragma unroll 8
        for (int u = 0; u < 64; ++u) acc += s_f0[u] * W1_0[u*64 + t];
        x0[n*64 + t] = acc * 0.125f;
    } else {
        const int c = (t - 64) >> 6;
        const int w = t & 63;
        float acc = 0.f;
        #pragma unroll 8
        for (int u = 0; u < 64; ++u) acc += s_f1[u*3 + c] * W1_1[u*64 + w];
        x1T[n*192 + c*64 + w] = acc * 0.125f;
    }
}

// ---------------- edge aggregation: one wave per node, 8-edge batches ----------------

__global__ __launch_bounds__(256) void edge_kernel(
    const float* __restrict__ eemb, const float* __restrict__ eattr,
    const int* __restrict__ esrc,
    const int* __restrict__ offsets, const int* __restrict__ csr,
    const float* __restrict__ x0g, const float* __restrict__ x1g,
    const float* __restrict__ Wr1, const float* __restrict__ Wr2,
    float* __restrict__ agg0, float* __restrict__ agg1)
{
    const int n = blockIdx.x * 4 + (threadIdx.x >> 6);
    if (n >= N_NODES) return;
    const int u = threadIdx.x & 63;
    const int j8 = u & 7;     // h-dim within edge slot

    const float rs8 = 0.35355339059327373f;
    const float rs3 = 0.57735026918962576f;

    // loop-invariant weights: wr2[k][j] = Wr2[j][k*64+u]*rs8 (rs3 folded into k=3)
    float wr2[4][8];
    #pragma unroll
    for (int k = 0; k < 4; ++k) {
        #pragma unroll
        for (int j = 0; j < 8; ++j) {
            float v = Wr2[j*256 + k*64 + u] * rs8;
            wr2[k][j] = (k == 3) ? v * rs3 : v;
        }
    }
    float wr1c[8];
    #pragma unroll
    for (int i = 0; i < 8; ++i) wr1c[i] = Wr1[i*8 + j8] * rs8;

    float A[8] = {0.f,0.f,0.f,0.f,0.f,0.f,0.f,0.f};

    const int start = offsets[n];
    const int cnt   = offsets[n+1] - start;

    for (int b = 0; b < cnt; b += 8) {
        const int m = cnt - b < 8 ? cnt - b : 8;
        const int slot = (u >> 3) < m ? (u >> 3) : 0;
        const int e = csr[start + b + slot];
        const int src = esrc[e];
        // per-slot h (one ssp per 8 edges, wave-wide)
        const float4 e0 = *reinterpret_cast<const float4*>(eemb + (size_t)e*8);
        const float4 e1 = *reinterpret_cast<const float4*>(eemb + (size_t)e*8 + 4);
        float pre = e0.x*wr1c[0] + e0.y*wr1c[1] + e0.z*wr1c[2] + e0.w*wr1c[3]
                  + e1.x*wr1c[4] + e1.y*wr1c[5] + e1.z*wr1c[6] + e1.w*wr1c[7];
        const float h  = ssp(pre);
        const float yl = eattr[(size_t)e*4 + (j8 & 3)];

        #pragma unroll
        for (int s = 0; s < 8; ++s) {
            if (s >= m) break;
            const int base = s * 8;
            const int ssrc = bcasti(src, base);
            const float* xp0 = x0g + (size_t)ssrc * 64;
            const float* xp1 = x1g + (size_t)ssrc * 192;
            const float xs0 = xp0[u];
            const float x1a = xp1[u];
            const float x1b = xp1[64 + u];
            const float x1c = xp1[128 + u];
            float w0 = 0.f, w1 = 0.f, w2 = 0.f, w3 = 0.f;
            #pragma unroll
            for (int j = 0; j < 8; ++j) {
                const float hj = bcastf(h, base + j);
                w0 += hj * wr2[0][j];
                w1 += hj * wr2[1][j];
                w2 += hj * wr2[2][j];
                w3 += hj * wr2[3][j];
            }
            const float y0 = bcastf(yl, base + 0);
            const float y1 = bcastf(yl, base + 1);
            const float y2 = bcastf(yl, base + 2);
            const float y3 = bcastf(yl, base + 3);
            A[0] += w0 * xs0 * y0;                         // m00
            const float t01 = w1 * xs0;
            A[1] += t01 * y1; A[2] += t01 * y2; A[3] += t01 * y3;   // m01
            const float t10 = w2 * y0;
            A[4] += t10 * x1a; A[5] += t10 * x1b; A[6] += t10 * x1c; // m10
            A[7] += w3 * (x1a*y1 + x1b*y2 + x1c*y3);       // m11 (rs3 folded)
        }
    }

    const float rs32 = 0.17677669529663687f;
    agg0[(size_t)n*128 + u]      = A[0] * rs32;
    agg0[(size_t)n*128 + 64 + u] = A[7] * rs32;
    #pragma unroll
    for (int c = 0; c < 3; ++c) {
        agg1[(size_t)n*384 + c*128 + u]      = A[1+c] * rs32;
        agg1[(size_t)n*384 + c*128 + 64 + u] = A[4+c] * rs32;
    }
}

// ---------------- epilogue A: n0 = agg0@W2_0*rs128 + (f0 x attr)@Wsc0/16 ----------------

#define NTA 16
__global__ __launch_bounds__(128) void epiA_kernel(
    const float* __restrict__ nf0, const float* __restrict__ nattr,
    const float* __restrict__ agg0,
    const float* __restrict__ W2_0, const float* __restrict__ Wsc0,
    float* __restrict__ out, float* __restrict__ gbuf)
{
    __shared__ float sA[384 * NTA];   // [i][nn], 24KB
    const int t = threadIdx.x;        // output col 0..127
    const int node0 = blockIdx.x * NTA;
    #pragma unroll 4
    for (int k = 0; k < 48; ++k) {
        int idx = k*128 + t;          // 0..6143
        int i = idx >> 4, nn = idx & 15;
        int node = node0 + nn;
        float v;
        if (i < 128) v = agg0[(size_t)node*128 + i];
        else {
            int uv = i - 128;
            v = nf0[(size_t)node*64 + (uv>>2)] * nattr[(size_t)node*4 + (uv&3)];
        }
        sA[idx] = v;
    }
    __syncthreads();
    float acc[NTA];
    #pragma unroll
    for (int nn = 0; nn < NTA; ++nn) acc[nn] = 0.f;
    const float rs128 = 0.088388347648318447f;
    for (int i = 0; i < 128; ++i) {
        const float wv = W2_0[i*128 + t] * rs128;
        const float4* p = reinterpret_cast<const float4*>(&sA[i*NTA]);
        #pragma unroll
        for (int q = 0; q < NTA/4; ++q) {
            float4 a = p[q];
            acc[q*4+0] += wv*a.x; acc[q*4+1] += wv*a.y;
            acc[q*4+2] += wv*a.z; acc[q*4+3] += wv*a.w;
        }
    }
    for (int uv = 0; uv < 256; ++uv) {
        const float wv = Wsc0[uv*128 + t] * 0.0625f;
        const float4* p = reinterpret_cast<const float4*>(&sA[(128+uv)*NTA]);
        #pragma unroll
        for (int q = 0; q < NTA/4; ++q) {
            float4 a = p[q];
            acc[q*4+0] += wv*a.x; acc[q*4+1] += wv*a.y;
            acc[q*4+2] += wv*a.z; acc[q*4+3] += wv*a.w;
        }
    }
    #pragma unroll
    for (int nn = 0; nn < NTA; ++nn) {
        const int node = node0 + nn;
        const float v = ssp(acc[nn]);
        if (t < 64) out[(size_t)node*256 + t] = nf0[(size_t)node*64 + t] + v;
        else        gbuf[(size_t)node*64 + (t-64)] = v;
    }
}

// ---------------- epilogue B: n1 = agg1@W2_1*rs128 + sc1; out = f1 + n1*gates ----------------

#define NTB 8
__global__ __launch_bounds__(192) void epiB_kernel(
    const float* __restrict__ nf1, const float* __restrict__ nattr,
    const float* __restrict__ agg1,
    const float* __restrict__ W2_1, const float* __restrict__ Wsc1,
    const float* __restrict__ gbuf, float* __restrict__ out)
{
    __shared__ float sA[3 * 384 * NTB];  // [(cc*384+i)][nn], 36KB
    const int t = threadIdx.x;           // 0..191
    const int w = t & 63, cc = t >> 6;
    const int node0 = blockIdx.x * NTB;
    // stage agg1 rows (3*128 per node): ws row q = c*128+i  ->  sA row c*384+i
    #pragma unroll 4
    for (int k = 0; k < 16; ++k) {
        int idx = k*192 + t;             // 0..3071
        int nn = idx & 7, q = idx >> 3;  // q = c*128+i, 0..383
        int c2 = q >> 7, i = q & 127;
        sA[(c2*384 + i)*NTB + nn] = agg1[(size_t)(node0+nn)*384 + q];
    }
    // stage g1 rows (3*256 per node): f1[u][c]*attr[v]
    #pragma unroll 4
    for (int k = 0; k < 32; ++k) {
        int idx = k*192 + t;             // 0..6143
        int nn = idx & 7, q = idx >> 3;  // 0..767
        int c2 = q >> 8, uv = q & 255;
        sA[(c2*384 + 128 + uv)*NTB + nn] =
            nf1[(size_t)(node0+nn)*192 + (uv>>2)*3 + c2] * nattr[(size_t)(node0+nn)*4 + (uv&3)];
    }
    __syncthreads();
    float acc[NTB];
    #pragma unroll
    for (int nn = 0; nn < NTB; ++nn) acc[nn] = 0.f;
    const float rs128 = 0.088388347648318447f;
    const int rowbase = cc * 384;
    for (int i = 0; i < 128; ++i) {
        const float wv = W2_1[i*64 + w] * rs128;
        const float4* p = reinterpret_cast<const float4*>(&sA[(rowbase+i)*NTB]);
        float4 a = p[0], b = p[1];
        acc[0] += wv*a.x; acc[1] += wv*a.y; acc[2] += wv*a.z; acc[3] += wv*a.w;
        acc[4] += wv*b.x; acc[5] += wv*b.y; acc[6] += wv*b.z; acc[7] += wv*b.w;
    }
    for (int uv = 0; uv < 256; ++uv) {
        const float wv = Wsc1[uv*64 + w] * 0.0625f;
        const float4* p = reinterpret_cast<const float4*>(&sA[(rowbase+128+uv)*NTB]);
        float4 a = p[0], b = p[1];
        acc[0] += wv*a.x; acc[1] += wv*a.y; acc[2] += wv*a.z; acc[3] += wv*a.w;
        acc[4] += wv*b.x; acc[5] += wv*b.y; acc[6] += wv*b.z; acc[7] += wv*b.w;
    }
    #pragma unroll
    for (int nn = 0; nn < NTB; ++nn) {
        const int node = node0 + nn;
        const float g = gbuf[(size_t)node*64 + w];
        out[(size_t)node*256 + 64 + w*3 + cc] =
            nf1[(size_t)node*192 + w*3 + cc] + acc[nn] * g;
    }
}

// ---------------- launch ----------------

extern "C" void kernel_launch(void* const* d_in, const int* in_sizes, int n_in,
                              void* d_out, int out_size, void* d_ws, size_t ws_size,
                              hipStream_t stream) {
    const float* nf0   = (const float*)d_in[0];
    const float* nf1   = (const float*)d_in[1];
    const float* nattr = (const float*)d_in[2];
    const float* eemb  = (const float*)d_in[3];
    const float* eattr = (const float*)d_in[4];
    const int*   esrc  = (const int*)d_in[5];
    const int*   edst  = (const int*)d_in[6];
    const float* W1_0  = (const float*)d_in[7];
    const float* W1_1  = (const float*)d_in[8];
    const float* Wr1   = (const float*)d_in[9];
    const float* Wr2   = (const float*)d_in[10];
    const float* W2_0  = (const float*)d_in[11];
    const float* W2_1  = (const float*)d_in[12];
    const float* Wsc0  = (const float*)d_in[13];
    const float* Wsc1  = (const float*)d_in[14];
    float* out = (float*)d_out;

    char* ws = (char*)d_ws;
    float* x0    = (float*)ws;  ws += (size_t)N_NODES*64*sizeof(float);
    float* x1T   = (float*)ws;  ws += (size_t)N_NODES*192*sizeof(float);
    int* counts  = (int*)ws;    ws += (size_t)N_NODES*sizeof(int);
    int* offsets = (int*)ws;    ws += (size_t)(N_NODES+1)*sizeof(int);
    int* cursor  = (int*)ws;    ws += (size_t)N_NODES*sizeof(int);
    int* csr     = (int*)ws;    ws += (size_t)N_EDGES*sizeof(int);
    float* agg0  = (float*)ws;  ws += (size_t)N_NODES*128*sizeof(float);
    float* agg1  = (float*)ws;  ws += (size_t)N_NODES*384*sizeof(float);
    float* gbuf  = x0;  // alias: x0 dead after edge_kernel; gbuf written by epiA after it

    hipMemsetAsync(counts, 0, N_NODES*sizeof(int), stream);
    node_pre_kernel<<<N_NODES, 256, 0, stream>>>(nf0, nf1, W1_0, W1_1, x0, x1T);
    count_kernel<<<(N_EDGES+255)/256, 256, 0, stream>>>(edst, counts, N_EDGES);
    scan_kernel<<<1, 1024, 0, stream>>>(counts, offsets, cursor, N_NODES);
    scatter_kernel<<<(N_EDGES+255)/256, 256, 0, stream>>>(edst, cursor, csr, N_EDGES);
    edge_kernel<<<(N_NODES+3)/4, 256, 0, stream>>>(eemb, eattr, esrc, offsets, csr,
        x0, x1T, Wr1, Wr2, agg0, agg1);
    epiA_kernel<<<N_NODES/NTA, 128, 0, stream>>>(nf0, nattr, agg0, W2_0, Wsc0, out, gbuf);
    epiB_kernel<<<N_NODES/NTB, 192, 0, stream>>>(nf1, nattr, agg1, W2_1, Wsc1, gbuf, out);
}